// Round 3
// baseline (832.410 us; speedup 1.0000x reference)
//
#include <hip/hip_runtime.h>
#include <cstdint>
#include <cstddef>

#define NNODES 100000
#define NEDGES 1600000
#define FIN    128
#define HID    64
#define NCLS   40

// ---------------- Threefry-2x32 (JAX-compatible) ----------------
__device__ __forceinline__ uint32_t rotl32(uint32_t x, uint32_t r) {
  return (x << r) | (x >> (32u - r));
}

__device__ __forceinline__ void threefry2x32(uint32_t k0, uint32_t k1,
                                             uint32_t c0, uint32_t c1,
                                             uint32_t& o0, uint32_t& o1) {
  const uint32_t ks2 = k0 ^ k1 ^ 0x1BD11BDAu;
  uint32_t x0 = c0 + k0;
  uint32_t x1 = c1 + k1;
#define TF_R(r) { x0 += x1; x1 = rotl32(x1, r); x1 ^= x0; }
  TF_R(13u) TF_R(15u) TF_R(26u) TF_R(6u)
  x0 += k1;  x1 += ks2 + 1u;
  TF_R(17u) TF_R(29u) TF_R(16u) TF_R(24u)
  x0 += ks2; x1 += k0 + 2u;
  TF_R(13u) TF_R(15u) TF_R(26u) TF_R(6u)
  x0 += k0;  x1 += k1 + 3u;
  TF_R(17u) TF_R(29u) TF_R(16u) TF_R(24u)
  x0 += k1;  x1 += ks2 + 4u;
  TF_R(13u) TF_R(15u) TF_R(26u) TF_R(6u)
  x0 += ks2; x1 += k0 + 5u;
#undef TF_R
  o0 = x0; o1 = x1;
}

// ---------------- degree / normalization ----------------
__global__ __launch_bounds__(256) void k_deg_init(float* __restrict__ deg) {
  int i = blockIdx.x * 256 + threadIdx.x;
  if (i < NNODES) deg[i] = 1.0f;  // self-loop
}

__global__ __launch_bounds__(256) void k_deg_count(const int* __restrict__ col,
                                                   float* __restrict__ deg) {
  int e = blockIdx.x * 256 + threadIdx.x;
  if (e < NEDGES) atomicAdd(&deg[col[e]], 1.0f);
}

__global__ __launch_bounds__(256) void k_rsqrt(float* __restrict__ deg) {
  int i = blockIdx.x * 256 + threadIdx.x;
  if (i < NNODES) deg[i] = rsqrtf(deg[i]);
}

// ---------------- dense transforms (x @ W) ----------------
__global__ __launch_bounds__(256) void k_mm1(const float* __restrict__ x,
                                             const float* __restrict__ W1,
                                             float* __restrict__ h1) {
  __shared__ float wl[FIN * HID];
  const int t = threadIdx.x;
  for (int i = t; i < FIN * HID; i += 256) wl[i] = W1[i];
  __syncthreads();
  const int r = blockIdx.x * 256 + t;
  if (r >= NNODES) return;
  float acc[HID];
#pragma unroll
  for (int f = 0; f < HID; ++f) acc[f] = 0.f;
  const float* xr = x + (size_t)r * FIN;
  for (int k = 0; k < FIN; k += 4) {
    const float4 xv = *reinterpret_cast<const float4*>(xr + k);
    const float* w0 = &wl[k * HID];
#pragma unroll
    for (int f = 0; f < HID; ++f) {
      acc[f] += xv.x * w0[f] + xv.y * w0[HID + f] +
                xv.z * w0[2 * HID + f] + xv.w * w0[3 * HID + f];
    }
  }
  float* hr = h1 + (size_t)r * HID;
#pragma unroll
  for (int f = 0; f < HID; f += 4) {
    *reinterpret_cast<float4*>(hr + f) =
        make_float4(acc[f], acc[f + 1], acc[f + 2], acc[f + 3]);
  }
}

__global__ __launch_bounds__(256) void k_mm2(const float* __restrict__ h2,
                                             const float* __restrict__ W2,
                                             float* __restrict__ g) {
  __shared__ float wl[HID * NCLS];
  const int t = threadIdx.x;
  for (int i = t; i < HID * NCLS; i += 256) wl[i] = W2[i];
  __syncthreads();
  const int r = blockIdx.x * 256 + t;
  if (r >= NNODES) return;
  float acc[NCLS];
#pragma unroll
  for (int f = 0; f < NCLS; ++f) acc[f] = 0.f;
  const float* xr = h2 + (size_t)r * HID;
  for (int k = 0; k < HID; k += 4) {
    const float4 xv = *reinterpret_cast<const float4*>(xr + k);
    const float* w0 = &wl[k * NCLS];
#pragma unroll
    for (int f = 0; f < NCLS; ++f) {
      acc[f] += xv.x * w0[f] + xv.y * w0[NCLS + f] +
                xv.z * w0[2 * NCLS + f] + xv.w * w0[3 * NCLS + f];
    }
  }
  float* gr = g + (size_t)r * NCLS;
#pragma unroll
  for (int f = 0; f < NCLS; f += 4) {
    *reinterpret_cast<float4*>(gr + f) =
        make_float4(acc[f], acc[f + 1], acc[f + 2], acc[f + 3]);
  }
}

// ---------------- aggregation: self term (init) + edge scatter ----------------
__global__ __launch_bounds__(256) void k_self1(const float* __restrict__ h,
                                               const float* __restrict__ dis,
                                               float* __restrict__ outb) {
  int idx = blockIdx.x * 256 + threadIdx.x;  // < N*HID = 6.4M
  if (idx >= NNODES * HID) return;
  int n = idx >> 6;
  float d = dis[n];
  outb[idx] = h[idx] * d * d;
}

__global__ __launch_bounds__(256) void k_edge1(const int* __restrict__ row,
                                               const int* __restrict__ col,
                                               const float* __restrict__ dis,
                                               const float* __restrict__ h,
                                               float* __restrict__ outb) {
  const long long tid = (long long)blockIdx.x * 256 + threadIdx.x;
  const int e = (int)(tid >> 6);
  const int f = (int)(tid & 63);
  if (e >= NEDGES) return;
  const int r = row[e];
  const int c = col[e];
  const float nrm = dis[r] * dis[c];
  atomicAdd(&outb[(size_t)c * HID + f], h[(size_t)r * HID + f] * nrm);
}

__global__ __launch_bounds__(256) void k_self2(const float* __restrict__ g,
                                               const float* __restrict__ dis,
                                               float* __restrict__ outb) {
  int idx = blockIdx.x * 256 + threadIdx.x;  // < N*NCLS = 4.0M
  if (idx >= NNODES * NCLS) return;
  int n = idx / NCLS;
  float d = dis[n];
  outb[idx] = g[idx] * d * d;
}

__global__ __launch_bounds__(256) void k_edge2(const int* __restrict__ row,
                                               const int* __restrict__ col,
                                               const float* __restrict__ dis,
                                               const float* __restrict__ g,
                                               float* __restrict__ outb) {
  const long long tid = (long long)blockIdx.x * 256 + threadIdx.x;
  const int e = (int)(tid >> 6);
  const int f = (int)(tid & 63);
  if (e >= NEDGES) return;
  if (f >= NCLS) return;
  const int r = row[e];
  const int c = col[e];
  const float nrm = dis[r] * dis[c];
  atomicAdd(&outb[(size_t)c * NCLS + f], g[(size_t)r * NCLS + f] * nrm);
}

// ---------------- bias + relu + dropout (JAX partitionable threefry) ----------
// jax_threefry_partitionable=True (default since 0.4.36):
// counter = 64-bit flat index via iota_2x32_shape -> (hi, lo); for size < 2^32
// that's (0, idx). For bit_width==32 the result is bits1 ^ bits2 (NOT a
// truncation -- that was round 1's bug).
__global__ __launch_bounds__(256) void k_reludrop(const float* __restrict__ agg,
                                                  const float* __restrict__ b1,
                                                  float* __restrict__ h2) {
  const uint32_t idx = blockIdx.x * 256 + threadIdx.x;
  if (idx >= (uint32_t)(NNODES * HID)) return;
  float v = agg[idx] + b1[idx & 63];
  v = fmaxf(v, 0.0f);
  uint32_t o0, o1;
  threefry2x32(0u, 42u, 0u, idx, o0, o1);
  const uint32_t bits = o0 ^ o1;
  const float u = __uint_as_float((bits >> 9) | 0x3f800000u) - 1.0f;
  const float keepf = (float)(1.0 - 0.4144);
  h2[idx] = (u < keepf) ? v / keepf : 0.0f;
}

// ---------------- bias + log_softmax (one wave per row) ----------------
__global__ __launch_bounds__(256) void k_lsm(float* __restrict__ outb,
                                             const float* __restrict__ b2) {
  const int gid = blockIdx.x * 256 + threadIdx.x;
  const int rowi = gid >> 6;
  const int lane = gid & 63;
  if (rowi >= NNODES) return;
  float* rp = outb + (size_t)rowi * NCLS;
  float v = -INFINITY;
  if (lane < NCLS) v = rp[lane] + b2[lane];
  float m = v;
#pragma unroll
  for (int off = 32; off > 0; off >>= 1) m = fmaxf(m, __shfl_xor(m, off, 64));
  float e = (lane < NCLS) ? expf(v - m) : 0.0f;
  float s = e;
#pragma unroll
  for (int off = 32; off > 0; off >>= 1) s += __shfl_xor(s, off, 64);
  const float ls = logf(s);
  if (lane < NCLS) rp[lane] = v - m - ls;
}

// ---------------- launch ----------------
extern "C" void kernel_launch(void* const* d_in, const int* in_sizes, int n_in,
                              void* d_out, int out_size, void* d_ws, size_t ws_size,
                              hipStream_t stream) {
  const float* x  = (const float*)d_in[0];
  const int*   ei = (const int*)d_in[1];
  const float* W1 = (const float*)d_in[2];
  const float* b1 = (const float*)d_in[3];
  const float* W2 = (const float*)d_in[4];
  const float* b2 = (const float*)d_in[5];
  float* out = (float*)d_out;

  const int* row = ei;           // edge_index[0]
  const int* col = ei + NEDGES;  // edge_index[1]

  float* ws  = (float*)d_ws;
  float* dis = ws;                         // N
  float* h1  = ws + NNODES;                // N*64 (reused as h2)
  float* o1b = h1 + (size_t)NNODES * HID;  // N*64
  float* g   = o1b + (size_t)NNODES * HID; // N*40

  const dim3 B(256);
  k_deg_init<<<dim3((NNODES + 255) / 256), B, 0, stream>>>(dis);
  k_deg_count<<<dim3((NEDGES + 255) / 256), B, 0, stream>>>(col, dis);
  k_rsqrt<<<dim3((NNODES + 255) / 256), B, 0, stream>>>(dis);

  k_mm1<<<dim3((NNODES + 255) / 256), B, 0, stream>>>(x, W1, h1);
  k_self1<<<dim3(NNODES * HID / 256), B, 0, stream>>>(h1, dis, o1b);
  k_edge1<<<dim3((int)(((long long)NEDGES * 64) / 256)), B, 0, stream>>>(row, col, dis, h1, o1b);
  k_reludrop<<<dim3(NNODES * HID / 256), B, 0, stream>>>(o1b, b1, h1);

  k_mm2<<<dim3((NNODES + 255) / 256), B, 0, stream>>>(h1, W2, g);
  k_self2<<<dim3(NNODES * NCLS / 256), B, 0, stream>>>(g, dis, out);
  k_edge2<<<dim3((int)(((long long)NEDGES * 64) / 256)), B, 0, stream>>>(row, col, dis, g, out);
  k_lsm<<<dim3((NNODES * 64 + 255) / 256), B, 0, stream>>>(out, b2);
}

// Round 4
// 745.531 us; speedup vs baseline: 1.1165x; 1.1165x over previous
//
#include <hip/hip_runtime.h>
#include <cstdint>
#include <cstddef>

#define NNODES 100000
#define NEDGES 1600000
#define FIN    128
#define HID    64
#define NCLS   40

// ---------------- Threefry-2x32 (JAX-compatible, partitionable) ----------------
__device__ __forceinline__ uint32_t rotl32(uint32_t x, uint32_t r) {
  return (x << r) | (x >> (32u - r));
}

__device__ __forceinline__ void threefry2x32(uint32_t k0, uint32_t k1,
                                             uint32_t c0, uint32_t c1,
                                             uint32_t& o0, uint32_t& o1) {
  const uint32_t ks2 = k0 ^ k1 ^ 0x1BD11BDAu;
  uint32_t x0 = c0 + k0;
  uint32_t x1 = c1 + k1;
#define TF_R(r) { x0 += x1; x1 = rotl32(x1, r); x1 ^= x0; }
  TF_R(13u) TF_R(15u) TF_R(26u) TF_R(6u)
  x0 += k1;  x1 += ks2 + 1u;
  TF_R(17u) TF_R(29u) TF_R(16u) TF_R(24u)
  x0 += ks2; x1 += k0 + 2u;
  TF_R(13u) TF_R(15u) TF_R(26u) TF_R(6u)
  x0 += k0;  x1 += k1 + 3u;
  TF_R(17u) TF_R(29u) TF_R(16u) TF_R(24u)
  x0 += k1;  x1 += ks2 + 4u;
  TF_R(13u) TF_R(15u) TF_R(26u) TF_R(6u)
  x0 += ks2; x1 += k0 + 5u;
#undef TF_R
  o0 = x0; o1 = x1;
}

// ---------------- CSR build ----------------
__global__ __launch_bounds__(256) void k_zero(int* __restrict__ cnt) {
  int i = blockIdx.x * 256 + threadIdx.x;
  if (i < NNODES) cnt[i] = 0;
}

__global__ __launch_bounds__(256) void k_count(const int* __restrict__ col,
                                               int* __restrict__ cnt) {
  int e = blockIdx.x * 256 + threadIdx.x;
  if (e < NEDGES) atomicAdd(&cnt[col[e]], 1);
}

// dis[i] = rsqrt(cnt[i] + 1)  (self-loop included)
__global__ __launch_bounds__(256) void k_dis(const int* __restrict__ cnt,
                                             float* __restrict__ dis) {
  int i = blockIdx.x * 256 + threadIdx.x;
  if (i < NNODES) dis[i] = rsqrtf((float)(cnt[i] + 1));
}

// single-workgroup exclusive scan of cnt -> offs (and cur copy)
__global__ __launch_bounds__(1024) void k_scan(const int* __restrict__ cnt,
                                               int* __restrict__ offs,
                                               int* __restrict__ cur) {
  __shared__ int part[1024];
  const int t = threadIdx.x;
  const int per = (NNODES + 1023) / 1024;  // 98
  const int base = t * per;
  int s = 0;
  for (int i = 0; i < per; ++i) {
    int j = base + i;
    if (j < NNODES) s += cnt[j];
  }
  part[t] = s;
  __syncthreads();
  for (int d = 1; d < 1024; d <<= 1) {
    int v = (t >= d) ? part[t - d] : 0;
    __syncthreads();
    part[t] += v;
    __syncthreads();
  }
  int ex = (t == 0) ? 0 : part[t - 1];
  for (int i = 0; i < per; ++i) {
    int j = base + i;
    if (j < NNODES) {
      offs[j] = ex;
      cur[j] = ex;
      ex += cnt[j];
    }
  }
}

__global__ __launch_bounds__(256) void k_fill(const int* __restrict__ row,
                                              const int* __restrict__ col,
                                              int* __restrict__ cur,
                                              int* __restrict__ elist) {
  int e = blockIdx.x * 256 + threadIdx.x;
  if (e >= NEDGES) return;
  int pos = atomicAdd(&cur[col[e]], 1);
  elist[pos] = row[e];
}

// ---------------- dense transforms, epilogue-scaled by dis[row] ----------------
__global__ __launch_bounds__(256) void k_mm1(const float* __restrict__ x,
                                             const float* __restrict__ W1,
                                             const float* __restrict__ dis,
                                             float* __restrict__ h1s) {
  __shared__ float wl[FIN * HID];
  const int t = threadIdx.x;
  for (int i = t; i < FIN * HID; i += 256) wl[i] = W1[i];
  __syncthreads();
  const int r = blockIdx.x * 256 + t;
  if (r >= NNODES) return;
  float acc[HID];
#pragma unroll
  for (int f = 0; f < HID; ++f) acc[f] = 0.f;
  const float* xr = x + (size_t)r * FIN;
  for (int k = 0; k < FIN; k += 4) {
    const float4 xv = *reinterpret_cast<const float4*>(xr + k);
    const float* w0 = &wl[k * HID];
#pragma unroll
    for (int f = 0; f < HID; ++f) {
      acc[f] += xv.x * w0[f] + xv.y * w0[HID + f] +
                xv.z * w0[2 * HID + f] + xv.w * w0[3 * HID + f];
    }
  }
  const float d = dis[r];
  float* hr = h1s + (size_t)r * HID;
#pragma unroll
  for (int f = 0; f < HID; f += 4) {
    *reinterpret_cast<float4*>(hr + f) =
        make_float4(acc[f] * d, acc[f + 1] * d, acc[f + 2] * d, acc[f + 3] * d);
  }
}

__global__ __launch_bounds__(256) void k_mm2(const float* __restrict__ h2,
                                             const float* __restrict__ W2,
                                             const float* __restrict__ dis,
                                             float* __restrict__ gs) {
  __shared__ float wl[HID * NCLS];
  const int t = threadIdx.x;
  for (int i = t; i < HID * NCLS; i += 256) wl[i] = W2[i];
  __syncthreads();
  const int r = blockIdx.x * 256 + t;
  if (r >= NNODES) return;
  float acc[NCLS];
#pragma unroll
  for (int f = 0; f < NCLS; ++f) acc[f] = 0.f;
  const float* xr = h2 + (size_t)r * HID;
  for (int k = 0; k < HID; k += 4) {
    const float4 xv = *reinterpret_cast<const float4*>(xr + k);
    const float* w0 = &wl[k * NCLS];
#pragma unroll
    for (int f = 0; f < NCLS; ++f) {
      acc[f] += xv.x * w0[f] + xv.y * w0[NCLS + f] +
                xv.z * w0[2 * NCLS + f] + xv.w * w0[3 * NCLS + f];
    }
  }
  const float d = dis[r];
  float* gr = gs + (size_t)r * NCLS;
#pragma unroll
  for (int f = 0; f < NCLS; f += 4) {
    *reinterpret_cast<float4*>(gr + f) =
        make_float4(acc[f] * d, acc[f + 1] * d, acc[f + 2] * d, acc[f + 3] * d);
  }
}

// ---------------- gather-aggregate layer 1 (+bias+relu+dropout) ----------------
// one wave per node; lane = feature
__global__ __launch_bounds__(256) void k_agg1(const float* __restrict__ h1s,
                                              const int* __restrict__ elist,
                                              const int* __restrict__ offs,
                                              const int* __restrict__ cnt,
                                              const float* __restrict__ dis,
                                              const float* __restrict__ b1,
                                              float* __restrict__ h2) {
  const int gid = blockIdx.x * 256 + threadIdx.x;
  const int node = gid >> 6;
  const int lane = gid & 63;
  if (node >= NNODES) return;
  const int base = offs[node];
  const int n = cnt[node];
  float acc = h1s[(size_t)node * HID + lane];  // self term (h' = h*dis)
  for (int k0 = 0; k0 < n; k0 += 64) {
    const int rem = n - k0;
    const int m = rem < 64 ? rem : 64;
    int src = 0;
    if (lane < m) src = elist[base + k0 + lane];
    for (int j = 0; j < m; ++j) {
      const int s = __shfl(src, j, 64);
      acc += h1s[(size_t)s * HID + lane];
    }
  }
  float v = acc * dis[node] + b1[lane];
  v = fmaxf(v, 0.0f);
  const uint32_t idx = (uint32_t)node * HID + lane;
  uint32_t o0, o1;
  threefry2x32(0u, 42u, 0u, idx, o0, o1);
  const uint32_t bits = o0 ^ o1;
  const float u = __uint_as_float((bits >> 9) | 0x3f800000u) - 1.0f;
  const float keepf = (float)(1.0 - 0.4144);
  h2[idx] = (u < keepf) ? v / keepf : 0.0f;
}

// ---------------- gather-aggregate layer 2 (+bias+log_softmax) ----------------
__global__ __launch_bounds__(256) void k_agg2(const float* __restrict__ gs,
                                              const int* __restrict__ elist,
                                              const int* __restrict__ offs,
                                              const int* __restrict__ cnt,
                                              const float* __restrict__ dis,
                                              const float* __restrict__ b2,
                                              float* __restrict__ out) {
  const int gid = blockIdx.x * 256 + threadIdx.x;
  const int node = gid >> 6;
  const int lane = gid & 63;
  if (node >= NNODES) return;
  const int base = offs[node];
  const int n = cnt[node];
  float acc = (lane < NCLS) ? gs[(size_t)node * NCLS + lane] : 0.0f;
  for (int k0 = 0; k0 < n; k0 += 64) {
    const int rem = n - k0;
    const int m = rem < 64 ? rem : 64;
    int src = 0;
    if (lane < m) src = elist[base + k0 + lane];
    for (int j = 0; j < m; ++j) {
      const int s = __shfl(src, j, 64);
      if (lane < NCLS) acc += gs[(size_t)s * NCLS + lane];
    }
  }
  float v = (lane < NCLS) ? (acc * dis[node] + b2[lane]) : -INFINITY;
  float mx = v;
#pragma unroll
  for (int off = 32; off > 0; off >>= 1) mx = fmaxf(mx, __shfl_xor(mx, off, 64));
  float e = (lane < NCLS) ? expf(v - mx) : 0.0f;
  float s = e;
#pragma unroll
  for (int off = 32; off > 0; off >>= 1) s += __shfl_xor(s, off, 64);
  const float ls = logf(s);
  if (lane < NCLS) out[(size_t)node * NCLS + lane] = v - mx - ls;
}

// ---------------- launch ----------------
extern "C" void kernel_launch(void* const* d_in, const int* in_sizes, int n_in,
                              void* d_out, int out_size, void* d_ws, size_t ws_size,
                              hipStream_t stream) {
  const float* x  = (const float*)d_in[0];
  const int*   ei = (const int*)d_in[1];
  const float* W1 = (const float*)d_in[2];
  const float* b1 = (const float*)d_in[3];
  const float* W2 = (const float*)d_in[4];
  const float* b2 = (const float*)d_in[5];
  float* out = (float*)d_out;

  const int* row = ei;           // edge_index[0]  (source)
  const int* col = ei + NEDGES;  // edge_index[1]  (destination)

  float* ws  = (float*)d_ws;
  float* dis = ws;                          // N
  float* h1s = ws + 100352;                 // N*64  (reused as gs after agg1)
  float* h2  = h1s + (size_t)NNODES * HID;  // N*64
  int* cnt   = (int*)(h2 + (size_t)NNODES * HID);  // N
  int* offs  = cnt + NNODES;                       // N
  int* cur   = offs + NNODES;                      // N
  int* elist = cur + NNODES;                       // E
  float* gs  = h1s;  // alias: h1s dead after k_agg1

  const dim3 B(256);
  const int GN   = (NNODES + 255) / 256;
  const int GE   = (NEDGES + 255) / 256;
  const int GNW  = (NNODES * 64 + 255) / 256;  // wave per node

  // CSR build + normalization
  k_zero <<<dim3(GN), B, 0, stream>>>(cnt);
  k_count<<<dim3(GE), B, 0, stream>>>(col, cnt);
  k_dis  <<<dim3(GN), B, 0, stream>>>(cnt, dis);
  k_scan <<<dim3(1), dim3(1024), 0, stream>>>(cnt, offs, cur);
  k_fill <<<dim3(GE), B, 0, stream>>>(row, col, cur, elist);

  // layer 1
  k_mm1 <<<dim3(GN), B, 0, stream>>>(x, W1, dis, h1s);
  k_agg1<<<dim3(GNW), B, 0, stream>>>(h1s, elist, offs, cnt, dis, b1, h2);

  // layer 2
  k_mm2 <<<dim3(GN), B, 0, stream>>>(h2, W2, dis, gs);
  k_agg2<<<dim3(GNW), B, 0, stream>>>(gs, elist, offs, cnt, dis, b2, out);
}

// Round 5
// 401.241 us; speedup vs baseline: 2.0746x; 1.8581x over previous
//
#include <hip/hip_runtime.h>
#include <cstdint>
#include <cstddef>

#define NNODES 100000
#define NEDGES 1600000
#define FIN    128
#define HID    64
#define NCLS   40
#define CHUNK  1024
#define NBLK   ((NNODES + CHUNK - 1) / CHUNK)  // 98

// ---------------- Threefry-2x32 (JAX-compatible, partitionable) ----------------
__device__ __forceinline__ uint32_t rotl32(uint32_t x, uint32_t r) {
  return (x << r) | (x >> (32u - r));
}

__device__ __forceinline__ void threefry2x32(uint32_t k0, uint32_t k1,
                                             uint32_t c0, uint32_t c1,
                                             uint32_t& o0, uint32_t& o1) {
  const uint32_t ks2 = k0 ^ k1 ^ 0x1BD11BDAu;
  uint32_t x0 = c0 + k0;
  uint32_t x1 = c1 + k1;
#define TF_R(r) { x0 += x1; x1 = rotl32(x1, r); x1 ^= x0; }
  TF_R(13u) TF_R(15u) TF_R(26u) TF_R(6u)
  x0 += k1;  x1 += ks2 + 1u;
  TF_R(17u) TF_R(29u) TF_R(16u) TF_R(24u)
  x0 += ks2; x1 += k0 + 2u;
  TF_R(13u) TF_R(15u) TF_R(26u) TF_R(6u)
  x0 += k0;  x1 += k1 + 3u;
  TF_R(17u) TF_R(29u) TF_R(16u) TF_R(24u)
  x0 += k1;  x1 += ks2 + 4u;
  TF_R(13u) TF_R(15u) TF_R(26u) TF_R(6u)
  x0 += ks2; x1 += k0 + 5u;
#undef TF_R
  o0 = x0; o1 = x1;
}

// ---------------- CSR build ----------------
__global__ __launch_bounds__(256) void k_zero(int* __restrict__ cnt) {
  int i = blockIdx.x * 256 + threadIdx.x;
  if (i < NNODES) cnt[i] = 0;
}

__global__ __launch_bounds__(256) void k_count(const int* __restrict__ col,
                                               int* __restrict__ cnt) {
  int e = blockIdx.x * 256 + threadIdx.x;
  if (e < NEDGES) atomicAdd(&cnt[col[e]], 1);
}

__global__ __launch_bounds__(256) void k_dis(const int* __restrict__ cnt,
                                             float* __restrict__ dis) {
  int i = blockIdx.x * 256 + threadIdx.x;
  if (i < NNODES) dis[i] = rsqrtf((float)(cnt[i] + 1));
}

// phase 1: per-block local exclusive scan (into locs) + block total (partial[b])
__global__ __launch_bounds__(256) void k_scan1(const int* __restrict__ cnt,
                                               int* __restrict__ locs,
                                               int* __restrict__ partial) {
  const int b = blockIdx.x, t = threadIdx.x;
  const int base = b * CHUNK + t * 4;
  int4 v = make_int4(0, 0, 0, 0);
  if (base + 3 < NNODES) {
    v = *reinterpret_cast<const int4*>(cnt + base);
  } else {
    if (base + 0 < NNODES) v.x = cnt[base + 0];
    if (base + 1 < NNODES) v.y = cnt[base + 1];
    if (base + 2 < NNODES) v.z = cnt[base + 2];
    if (base + 3 < NNODES) v.w = cnt[base + 3];
  }
  const int s = v.x + v.y + v.z + v.w;
  const int lane = t & 63, wid = t >> 6;
  int sc = s;
#pragma unroll
  for (int off = 1; off < 64; off <<= 1) {
    int u = __shfl_up(sc, off, 64);
    if (lane >= off) sc += u;
  }
  __shared__ int wsum[4];
  if (lane == 63) wsum[wid] = sc;
  __syncthreads();
  int wadd = 0;
  for (int w = 0; w < wid; ++w) wadd += wsum[w];
  const int ex = sc - s + wadd;  // thread's exclusive prefix within block
  const int o0 = ex, o1 = ex + v.x, o2 = o1 + v.y, o3 = o2 + v.z;
  if (base + 3 < NNODES) {
    *reinterpret_cast<int4*>(locs + base) = make_int4(o0, o1, o2, o3);
  } else {
    if (base + 0 < NNODES) locs[base + 0] = o0;
    if (base + 1 < NNODES) locs[base + 1] = o1;
    if (base + 2 < NNODES) locs[base + 2] = o2;
    if (base + 3 < NNODES) locs[base + 3] = o3;
  }
  if (t == 255) partial[b] = ex + s;  // block total
}

// phase 2: one wave turns partial[] (NBLK totals) into exclusive block offsets
__global__ __launch_bounds__(64) void k_scan2(int* __restrict__ partial) {
  const int t = threadIdx.x;  // 0..63, covers 2 slots each
  const int i0 = 2 * t, i1 = 2 * t + 1;
  const int p0 = (i0 < NBLK) ? partial[i0] : 0;
  const int p1 = (i1 < NBLK) ? partial[i1] : 0;
  const int s = p0 + p1;
  int sc = s;
#pragma unroll
  for (int off = 1; off < 64; off <<= 1) {
    int u = __shfl_up(sc, off, 64);
    if (t >= off) sc += u;
  }
  const int ex = sc - s;
  if (i0 < NBLK) partial[i0] = ex;
  if (i1 < NBLK) partial[i1] = ex + p0;
}

// phase 3: offs = locs + partial[b]; cur = offs
__global__ __launch_bounds__(256) void k_scan3(const int* __restrict__ locs,
                                               const int* __restrict__ partial,
                                               int* __restrict__ offs,
                                               int* __restrict__ cur) {
  const int b = blockIdx.x, t = threadIdx.x;
  const int base = b * CHUNK + t * 4;
  const int add = partial[b];
  if (base + 3 < NNODES) {
    int4 v = *reinterpret_cast<const int4*>(locs + base);
    v.x += add; v.y += add; v.z += add; v.w += add;
    *reinterpret_cast<int4*>(offs + base) = v;
    *reinterpret_cast<int4*>(cur + base) = v;
  } else {
    for (int i = 0; i < 4; ++i) {
      if (base + i < NNODES) {
        int v = locs[base + i] + add;
        offs[base + i] = v;
        cur[base + i] = v;
      }
    }
  }
}

__global__ __launch_bounds__(256) void k_fill(const int* __restrict__ row,
                                              const int* __restrict__ col,
                                              int* __restrict__ cur,
                                              int* __restrict__ elist) {
  int e = blockIdx.x * 256 + threadIdx.x;
  if (e >= NEDGES) return;
  int pos = atomicAdd(&cur[col[e]], 1);
  elist[pos] = row[e];
}

// ---------------- dense transforms, epilogue-scaled by dis[row] ----------------
__global__ __launch_bounds__(256) void k_mm1(const float* __restrict__ x,
                                             const float* __restrict__ W1,
                                             const float* __restrict__ dis,
                                             float* __restrict__ h1s) {
  __shared__ float wl[FIN * HID];
  const int t = threadIdx.x;
  for (int i = t; i < FIN * HID; i += 256) wl[i] = W1[i];
  __syncthreads();
  const int r = blockIdx.x * 256 + t;
  if (r >= NNODES) return;
  float acc[HID];
#pragma unroll
  for (int f = 0; f < HID; ++f) acc[f] = 0.f;
  const float* xr = x + (size_t)r * FIN;
  for (int k = 0; k < FIN; k += 4) {
    const float4 xv = *reinterpret_cast<const float4*>(xr + k);
    const float* w0 = &wl[k * HID];
#pragma unroll
    for (int f = 0; f < HID; ++f) {
      acc[f] += xv.x * w0[f] + xv.y * w0[HID + f] +
                xv.z * w0[2 * HID + f] + xv.w * w0[3 * HID + f];
    }
  }
  const float d = dis[r];
  float* hr = h1s + (size_t)r * HID;
#pragma unroll
  for (int f = 0; f < HID; f += 4) {
    *reinterpret_cast<float4*>(hr + f) =
        make_float4(acc[f] * d, acc[f + 1] * d, acc[f + 2] * d, acc[f + 3] * d);
  }
}

__global__ __launch_bounds__(256) void k_mm2(const float* __restrict__ h2,
                                             const float* __restrict__ W2,
                                             const float* __restrict__ dis,
                                             float* __restrict__ gs) {
  __shared__ float wl[HID * NCLS];
  const int t = threadIdx.x;
  for (int i = t; i < HID * NCLS; i += 256) wl[i] = W2[i];
  __syncthreads();
  const int r = blockIdx.x * 256 + t;
  if (r >= NNODES) return;
  float acc[NCLS];
#pragma unroll
  for (int f = 0; f < NCLS; ++f) acc[f] = 0.f;
  const float* xr = h2 + (size_t)r * HID;
  for (int k = 0; k < HID; k += 4) {
    const float4 xv = *reinterpret_cast<const float4*>(xr + k);
    const float* w0 = &wl[k * NCLS];
#pragma unroll
    for (int f = 0; f < NCLS; ++f) {
      acc[f] += xv.x * w0[f] + xv.y * w0[NCLS + f] +
                xv.z * w0[2 * NCLS + f] + xv.w * w0[3 * NCLS + f];
    }
  }
  const float d = dis[r];
  float* gr = gs + (size_t)r * NCLS;
#pragma unroll
  for (int f = 0; f < NCLS; f += 4) {
    *reinterpret_cast<float4*>(gr + f) =
        make_float4(acc[f] * d, acc[f + 1] * d, acc[f + 2] * d, acc[f + 3] * d);
  }
}

// ---------------- gather-aggregate layer 1 (+bias+relu+dropout) ----------------
__global__ __launch_bounds__(256) void k_agg1(const float* __restrict__ h1s,
                                              const int* __restrict__ elist,
                                              const int* __restrict__ offs,
                                              const int* __restrict__ cnt,
                                              const float* __restrict__ dis,
                                              const float* __restrict__ b1,
                                              float* __restrict__ h2) {
  const int gid = blockIdx.x * 256 + threadIdx.x;
  const int node = gid >> 6;
  const int lane = gid & 63;
  if (node >= NNODES) return;
  const int base = offs[node];
  const int n = cnt[node];
  float acc0 = h1s[(size_t)node * HID + lane];  // self term (h' = h*dis)
  float acc1 = 0.f, acc2 = 0.f, acc3 = 0.f;
  for (int k0 = 0; k0 < n; k0 += 64) {
    const int rem = n - k0;
    const int m = rem < 64 ? rem : 64;
    int src = 0;
    if (lane < m) src = elist[base + k0 + lane];
    int j = 0;
    for (; j + 4 <= m; j += 4) {
      const int s0 = __shfl(src, j, 64);
      const int s1 = __shfl(src, j + 1, 64);
      const int s2 = __shfl(src, j + 2, 64);
      const int s3 = __shfl(src, j + 3, 64);
      const float a0 = h1s[(size_t)s0 * HID + lane];
      const float a1 = h1s[(size_t)s1 * HID + lane];
      const float a2 = h1s[(size_t)s2 * HID + lane];
      const float a3 = h1s[(size_t)s3 * HID + lane];
      acc0 += a0; acc1 += a1; acc2 += a2; acc3 += a3;
    }
    for (; j < m; ++j) {
      const int s0 = __shfl(src, j, 64);
      acc0 += h1s[(size_t)s0 * HID + lane];
    }
  }
  const float acc = (acc0 + acc1) + (acc2 + acc3);
  float v = acc * dis[node] + b1[lane];
  v = fmaxf(v, 0.0f);
  const uint32_t idx = (uint32_t)node * HID + lane;
  uint32_t o0, o1;
  threefry2x32(0u, 42u, 0u, idx, o0, o1);
  const uint32_t bits = o0 ^ o1;
  const float u = __uint_as_float((bits >> 9) | 0x3f800000u) - 1.0f;
  const float keepf = (float)(1.0 - 0.4144);
  h2[idx] = (u < keepf) ? v / keepf : 0.0f;
}

// ---------------- gather-aggregate layer 2 (+bias+log_softmax) ----------------
__global__ __launch_bounds__(256) void k_agg2(const float* __restrict__ gs,
                                              const int* __restrict__ elist,
                                              const int* __restrict__ offs,
                                              const int* __restrict__ cnt,
                                              const float* __restrict__ dis,
                                              const float* __restrict__ b2,
                                              float* __restrict__ out) {
  const int gid = blockIdx.x * 256 + threadIdx.x;
  const int node = gid >> 6;
  const int lane = gid & 63;
  if (node >= NNODES) return;
  const int base = offs[node];
  const int n = cnt[node];
  float acc0 = (lane < NCLS) ? gs[(size_t)node * NCLS + lane] : 0.0f;
  float acc1 = 0.f, acc2 = 0.f, acc3 = 0.f;
  for (int k0 = 0; k0 < n; k0 += 64) {
    const int rem = n - k0;
    const int m = rem < 64 ? rem : 64;
    int src = 0;
    if (lane < m) src = elist[base + k0 + lane];
    int j = 0;
    for (; j + 4 <= m; j += 4) {
      const int s0 = __shfl(src, j, 64);
      const int s1 = __shfl(src, j + 1, 64);
      const int s2 = __shfl(src, j + 2, 64);
      const int s3 = __shfl(src, j + 3, 64);
      // loads stay within ws (gs aliases an N*64 region), lanes >= NCLS unused
      const float a0 = gs[(size_t)s0 * NCLS + lane];
      const float a1 = gs[(size_t)s1 * NCLS + lane];
      const float a2 = gs[(size_t)s2 * NCLS + lane];
      const float a3 = gs[(size_t)s3 * NCLS + lane];
      if (lane < NCLS) { acc0 += a0; acc1 += a1; acc2 += a2; acc3 += a3; }
    }
    for (; j < m; ++j) {
      const int s0 = __shfl(src, j, 64);
      if (lane < NCLS) acc0 += gs[(size_t)s0 * NCLS + lane];
    }
  }
  const float acc = (acc0 + acc1) + (acc2 + acc3);
  float v = (lane < NCLS) ? (acc * dis[node] + b2[lane]) : -INFINITY;
  float mx = v;
#pragma unroll
  for (int off = 32; off > 0; off >>= 1) mx = fmaxf(mx, __shfl_xor(mx, off, 64));
  float e = (lane < NCLS) ? expf(v - mx) : 0.0f;
  float s = e;
#pragma unroll
  for (int off = 32; off > 0; off >>= 1) s += __shfl_xor(s, off, 64);
  const float ls = logf(s);
  if (lane < NCLS) out[(size_t)node * NCLS + lane] = v - mx - ls;
}

// ---------------- launch ----------------
extern "C" void kernel_launch(void* const* d_in, const int* in_sizes, int n_in,
                              void* d_out, int out_size, void* d_ws, size_t ws_size,
                              hipStream_t stream) {
  const float* x  = (const float*)d_in[0];
  const int*   ei = (const int*)d_in[1];
  const float* W1 = (const float*)d_in[2];
  const float* b1 = (const float*)d_in[3];
  const float* W2 = (const float*)d_in[4];
  const float* b2 = (const float*)d_in[5];
  float* out = (float*)d_out;

  const int* row = ei;           // edge_index[0]  (source)
  const int* col = ei + NEDGES;  // edge_index[1]  (destination)

  float* ws  = (float*)d_ws;
  float* dis = ws;                          // N
  float* h1s = ws + 100352;                 // N*64  (reused as gs after agg1)
  float* h2  = h1s + (size_t)NNODES * HID;  // N*64
  int* cnt   = (int*)(h2 + (size_t)NNODES * HID);  // N
  int* offs  = cnt + NNODES;                       // N
  int* cur   = offs + NNODES;                      // N
  int* locs  = cur + NNODES;                       // N
  int* partial = locs + NNODES;                    // NBLK (+pad)
  int* elist = partial + 256;                      // E
  float* gs  = h1s;  // alias: h1s dead after k_agg1

  const dim3 B(256);
  const int GN  = (NNODES + 255) / 256;
  const int GE  = (NEDGES + 255) / 256;
  const int GNW = (NNODES * 64 + 255) / 256;  // wave per node

  // CSR build + normalization
  k_zero <<<dim3(GN), B, 0, stream>>>(cnt);
  k_count<<<dim3(GE), B, 0, stream>>>(col, cnt);
  k_dis  <<<dim3(GN), B, 0, stream>>>(cnt, dis);
  k_scan1<<<dim3(NBLK), B, 0, stream>>>(cnt, locs, partial);
  k_scan2<<<dim3(1), dim3(64), 0, stream>>>(partial);
  k_scan3<<<dim3(NBLK), B, 0, stream>>>(locs, partial, offs, cur);
  k_fill <<<dim3(GE), B, 0, stream>>>(row, col, cur, elist);

  // layer 1
  k_mm1 <<<dim3(GN), B, 0, stream>>>(x, W1, dis, h1s);
  k_agg1<<<dim3(GNW), B, 0, stream>>>(h1s, elist, offs, cnt, dis, b1, h2);

  // layer 2
  k_mm2 <<<dim3(GN), B, 0, stream>>>(h2, W2, dis, gs);
  k_agg2<<<dim3(GNW), B, 0, stream>>>(gs, elist, offs, cnt, dis, b2, out);
}